// Round 11
// baseline (139.168 us; speedup 1.0000x reference)
//
#include <hip/hip_runtime.h>

#define F_IN 165
#define HID  32
#define TROWS 32                 // N=500000 = 32*15625 exact
#define XBYTES 21120             // x source bytes per tile (32*660)
#define HCB    4096              // h/c source bytes per tile (32*128)

// Phase-split LDS buffers (per parity):
//   bufA: x cols 0-95   -> [32 rows][400B] = 12800 B (384B data + 16B pad)
//   bufB: x cols 96-164 -> [32][304B] = 9728 B (276B data + pad)
//         + h [32][144B] = 4608 B + c [32][128B] = 4096 B
#define BUFA_SZ 12800
#define BXSZ    9728
#define BHOFF   9728
#define BCOFF   (BHOFF + 4608)   // 14336
#define BUFB_SZ (BCOFF + 4096)   // 18432
#define BOFF0   (2 * BUFA_SZ)    // 25600
#define PYOFF   (BOFF0 + 2 * BUFB_SZ)   // 62464; +512 py = 62976 B LDS

typedef __attribute__((ext_vector_type(8))) __bf16 bf16x8;
typedef __attribute__((ext_vector_type(4))) float  f32x4;

typedef __attribute__((address_space(1))) void as1_void;
typedef __attribute__((address_space(3))) void as3_void;

__device__ __forceinline__ void gload_lds16(const void* g, void* l) {
    __builtin_amdgcn_global_load_lds(
        reinterpret_cast<as1_void*>(reinterpret_cast<uintptr_t>(g)),
        reinterpret_cast<as3_void*>((uint32_t)reinterpret_cast<uintptr_t>(l)),
        16, 0, 0);
}
__device__ __forceinline__ void gload_lds4(const void* g, void* l) {
    __builtin_amdgcn_global_load_lds(
        reinterpret_cast<as1_void*>(reinterpret_cast<uintptr_t>(g)),
        reinterpret_cast<as3_void*>((uint32_t)reinterpret_cast<uintptr_t>(l)),
        4, 0, 0);
}

__device__ __forceinline__ float fast_sigmoid(float x) {
    return __builtin_amdgcn_rcpf(1.f + __builtin_amdgcn_exp2f(-1.4426950408889634f * x));
}
__device__ __forceinline__ float fast_tanh(float x) {
    return 1.f - 2.f * __builtin_amdgcn_rcpf(1.f + __builtin_amdgcn_exp2f(2.8853900817779268f * x));
}

// ---- workspace (prepacked): frag table 56 slots x 64 lanes x 16B; bias at +57344
#define FRAG_BYTES 57344

struct PrepParams {
    const float *W0, *W1, *W2, *W3;
    const float *Wc0, *Wc1, *Wc2, *Wc3;
    const float *b0, *b1, *b2, *b3;
    const float *bc0, *bc1, *bc2, *bc3;
    char* ws;
};

__global__ void gclstm_prep(PrepParams pp) {
    int t = blockIdx.x * 256 + threadIdx.x;
    if (t < 56 * 64) {
        int slot = t >> 6, l = t & 63;
        int ks = slot >> 3, g = (slot >> 1) & 3, hf = slot & 1;
        int cl = l & 15, q = l >> 4;
        const float* W = (ks < 6)
            ? (g==0 ? pp.W0  : g==1 ? pp.W1  : g==2 ? pp.W2  : pp.W3)
            : (g==0 ? pp.Wc0 : g==1 ? pp.Wc1 : g==2 ? pp.Wc2 : pp.Wc3);
        bf16x8 v;
#pragma unroll
        for (int j = 0; j < 8; ++j) {
            float f = 0.f;
            if (ks < 6) {
                int k = ks * 32 + q * 8 + j;
                if (k < F_IN) f = W[k * HID + hf * 16 + cl];
            } else {
                int k = q * 8 + j;
                f = W[k * HID + hf * 16 + cl];
            }
            v[j] = (__bf16)f;
        }
        *(bf16x8*)(pp.ws + slot * 1024 + l * 16) = v;
    } else if (t < 56 * 64 + 128) {
        int i = t - 56 * 64;
        int g = i >> 5, col = i & 31;
        const float* B  = g==0 ? pp.b0  : g==1 ? pp.b1  : g==2 ? pp.b2  : pp.b3;
        const float* Bc = g==0 ? pp.bc0 : g==1 ? pp.bc1 : g==2 ? pp.bc2 : pp.bc3;
        ((float*)(pp.ws + FRAG_BYTES))[i] = B[col] + Bc[col];
    }
}

struct Params {
    const float *x, *h, *c, *Wl, *bl;
    const char* ws;
    float *y, *h0o, *c0o;
    int n, nt;
};

// ---- phase-A staging: x cols 0-95 into [32][400] padded rows ----
// dest byte o: r = o/400 (magic /25 of o>>4), col = o-400r;
// src = o + 260r when col<384 (data), else clamp 0 (pad, never read).
// ops/wave: w0,w1 = 4 (3 full + 1 small); w2,w3 = 3 full.
__device__ __forceinline__ void stage_A(const Params& p, char* dst, long tt,
                                        int w, int l) {
    const char* xb = (const char*)p.x + tt * (long)XBYTES;
#pragma unroll
    for (int i = 0; i < 3; ++i) {
        int o = (w * 3 + i) * 1024 + l * 16;
        int r = ((o >> 4) * 2622) >> 16;
        int col = o - 400 * r;
        int src = (col < 384) ? (o + 260 * r) : 0;
        gload_lds16(xb + src, dst + o);
    }
    if (w < 2) {
        int o = 12288 + w * 256 + l * 4;
        int r = ((o >> 4) * 2622) >> 16;
        int col = o - 400 * r;
        int src = (col < 384) ? (o + 260 * r) : 0;
        gload_lds4(xb + src, dst + o);
    }
}

// ---- phase-B staging: x cols 96-164 ([32][304]), h ([32][144]), c ([32][128])
// xB dest o: r = o/304, col = o-304r; src = o+384+356r when col<276
//   (window at col 272 straddles 4B of pad: reads into next row, lands in pad).
// h dest o: r = o/144, col = o-144r; src = o-16r when col<128.
// ops/wave: w0=6, w1=5, w2=5, w3=5.
__device__ __forceinline__ void stage_B(const Params& p, char* dstB, long tt,
                                        int w, int l) {
    const char* xb = (const char*)p.x + tt * (long)XBYTES;
    const char* hb = (const char*)p.h + tt * (long)HCB;
    const char* cb = (const char*)p.c + tt * (long)HCB;
    if (w == 0) {
#pragma unroll
        for (int i = 0; i < 3; ++i) {
            int o = i * 1024 + l * 16;
            int r = ((o >> 4) * 3450) >> 16;
            int col = o - 304 * r;
            int src = (col < 276) ? (o + 384 + 356 * r) : 0;
            gload_lds16(xb + src, dstB + o);
        }
#pragma unroll
        for (int i = 0; i < 2; ++i) {
            int o = 9216 + i * 256 + l * 4;
            int r = ((o >> 4) * 3450) >> 16;
            int col = o - 304 * r;
            int src = (col < 276) ? (o + 384 + 356 * r) : 0;
            gload_lds4(xb + src, dstB + o);
        }
        {   // h small op 0
            int o = 4096 + l * 4;
            int r = ((o >> 4) * 7282) >> 16;
            int col = o - 144 * r;
            int src = (col < 128) ? (o - 16 * r) : 0;
            gload_lds4(hb + src, dstB + BHOFF + o);
        }
    } else if (w < 3) {
#pragma unroll
        for (int i = 0; i < 3; ++i) {
            int o = ((w - 1) * 3 + 3 + i) * 1024 + l * 16;   // x units 3-8
            int r = ((o >> 4) * 3450) >> 16;
            int col = o - 304 * r;
            int src = (col < 276) ? (o + 384 + 356 * r) : 0;
            gload_lds16(xb + src, dstB + o);
        }
#pragma unroll
        for (int i = 0; i < 2; ++i) {                        // h full units
            int o = ((w - 1) * 2 + i) * 1024 + l * 16;
            int r = ((o >> 4) * 7282) >> 16;
            int col = o - 144 * r;
            int src = (col < 128) ? (o - 16 * r) : 0;
            gload_lds16(hb + src, dstB + BHOFF + o);
        }
    } else {
#pragma unroll
        for (int i = 0; i < 4; ++i)                          // c units (direct)
            gload_lds16(cb + i * 1024 + l * 16, dstB + BCOFF + i * 1024 + l * 16);
        {   // h small op 1
            int o = 4096 + 256 + l * 4;
            int r = ((o >> 4) * 7282) >> 16;
            int col = o - 144 * r;
            int src = (col < 128) ? (o - 16 * r) : 0;
            gload_lds4(hb + src, dstB + BHOFF + o);
        }
    }
}

// 256 thr = 4 waves = {sub rows-half} x {hf cols-half}. K-phase-split pipeline:
// each half-stage is WAITED one full iteration after issue (lead >> latency+
// service), so exposed wait ~0. Per-wave vmem order/iter: [A][B][st 8][y 1];
// waitA/waitB both = vmcnt(A_w+B_w+9) at their points (19/18/17/17).
__global__ __launch_bounds__(256, 2) void gclstm_main(Params p) {
    __shared__ char smem[PYOFF + 512];
    float* py = (float*)(smem + PYOFF);   // [sub*2+hf][16 rows][2 cls]

    const int tid = threadIdx.x;
    const int w   = tid >> 6;
    const int sub = w >> 1, hf = w & 1;
    const int l   = tid & 63;
    const int cl  = l & 15, q = l >> 4;
    const int col = hf * 16 + cl;

    bf16x8 bw[4][7];
#pragma unroll
    for (int ks = 0; ks < 7; ++ks)
#pragma unroll
        for (int g = 0; g < 4; ++g)
            bw[g][ks] = *(const bf16x8*)(p.ws + (ks * 8 + g * 2 + hf) * 1024 + l * 16);

    const float* biasT = (const float*)(p.ws + FRAG_BYTES);
    float bias[4];
#pragma unroll
    for (int g = 0; g < 4; ++g) bias[g] = biasT[g * 32 + col];
    const float wl0 = p.Wl[col * 2 + 0];
    const float wl1 = p.Wl[col * 2 + 1];
    const float bl0 = p.bl[0], bl1 = p.bl[1];

    const int nt = p.nt, stride = gridDim.x;
    int t = blockIdx.x;
    if (t >= nt) return;

    const int lrow = sub * 16 + cl;
    const int drow = sub * 16 + 4 * q;

    // prologue: stage both halves of tile t into parity 0, drain
    stage_A(p, smem, t, w, l);
    stage_B(p, smem + BOFF0, t, w, l);
    asm volatile("s_waitcnt vmcnt(0)" ::: "memory");
    __builtin_amdgcn_s_barrier();
    asm volatile("" ::: "memory");

    int par = 0;
    while (true) {
        const int tn = t + stride;
        const bool more = (tn < nt);
        const long td = more ? (long)tn : 0;   // dummy keeps counts uniform

        // ---- issue stage A(t+1) to opposite parity, wait for A(t) ----
        stage_A(p, smem + (par ^ 1) * BUFA_SZ, td, w, l);
        if (w == 0)      asm volatile("s_waitcnt vmcnt(19)" ::: "memory");
        else if (w == 1) asm volatile("s_waitcnt vmcnt(18)" ::: "memory");
        else             asm volatile("s_waitcnt vmcnt(17)" ::: "memory");
        __builtin_amdgcn_s_barrier();
        asm volatile("" ::: "memory");

        // ---- consume phase A: MFMA ks 0-2 from bufA[par] ----
        const char* xrowA = smem + par * BUFA_SZ + lrow * 400;
        f32x4 acc[4];
#pragma unroll
        for (int g = 0; g < 4; ++g) acc[g] = (f32x4){0.f, 0.f, 0.f, 0.f};
#pragma unroll
        for (int ks = 0; ks < 3; ++ks) {
            float4 a = *(const float4*)(xrowA + ks * 128 + q * 32);
            float4 b = *(const float4*)(xrowA + ks * 128 + q * 32 + 16);
            bf16x8 af;
            af[0]=(__bf16)a.x; af[1]=(__bf16)a.y; af[2]=(__bf16)a.z; af[3]=(__bf16)a.w;
            af[4]=(__bf16)b.x; af[5]=(__bf16)b.y; af[6]=(__bf16)b.z; af[7]=(__bf16)b.w;
#pragma unroll
            for (int g = 0; g < 4; ++g)
                acc[g] = __builtin_amdgcn_mfma_f32_16x16x32_bf16(af, bw[g][ks], acc[g], 0, 0, 0);
        }

        // ---- issue stage B(t+1), wait for B(t) ----
        stage_B(p, smem + BOFF0 + (par ^ 1) * BUFB_SZ, td, w, l);
        if (w == 0)      asm volatile("s_waitcnt vmcnt(19)" ::: "memory");
        else if (w == 1) asm volatile("s_waitcnt vmcnt(18)" ::: "memory");
        else             asm volatile("s_waitcnt vmcnt(17)" ::: "memory");
        __builtin_amdgcn_s_barrier();
        asm volatile("" ::: "memory");

        // ---- consume phase B: ks 3-5 + h, then epilogue ----
        const char* bufb  = smem + BOFF0 + par * BUFB_SZ;
        const char* xrowB = bufb + lrow * 304;
        {
            float4 a = *(const float4*)(xrowB + q * 32);
            float4 b = *(const float4*)(xrowB + q * 32 + 16);
            bf16x8 af;
            af[0]=(__bf16)a.x; af[1]=(__bf16)a.y; af[2]=(__bf16)a.z; af[3]=(__bf16)a.w;
            af[4]=(__bf16)b.x; af[5]=(__bf16)b.y; af[6]=(__bf16)b.z; af[7]=(__bf16)b.w;
#pragma unroll
            for (int g = 0; g < 4; ++g)
                acc[g] = __builtin_amdgcn_mfma_f32_16x16x32_bf16(af, bw[g][3], acc[g], 0, 0, 0);
        }
        {
            float4 a = *(const float4*)(xrowB + 128 + q * 32);
            float4 b = *(const float4*)(xrowB + 128 + q * 32 + 16);
            bf16x8 af;
            af[0]=(__bf16)a.x; af[1]=(__bf16)a.y; af[2]=(__bf16)a.z; af[3]=(__bf16)a.w;
            af[4]=(__bf16)b.x; af[5]=(__bf16)b.y; af[6]=(__bf16)b.z; af[7]=(__bf16)b.w;
#pragma unroll
            for (int g = 0; g < 4; ++g)
                acc[g] = __builtin_amdgcn_mfma_f32_16x16x32_bf16(af, bw[g][4], acc[g], 0, 0, 0);
        }
        {   // ks=5 tail: k=160-164 on q==0 lanes
            float4 tq = *(const float4*)(xrowB + 256);
            float t4  = *(const float*)(xrowB + 272);
            bool qz = (q == 0);
            bf16x8 af;
            af[0] = (__bf16)(qz ? tq.x : 0.f);
            af[1] = (__bf16)(qz ? tq.y : 0.f);
            af[2] = (__bf16)(qz ? tq.z : 0.f);
            af[3] = (__bf16)(qz ? tq.w : 0.f);
            af[4] = (__bf16)(qz ? t4   : 0.f);
            af[5] = (__bf16)0.f; af[6] = (__bf16)0.f; af[7] = (__bf16)0.f;
#pragma unroll
            for (int g = 0; g < 4; ++g)
                acc[g] = __builtin_amdgcn_mfma_f32_16x16x32_bf16(af, bw[g][5], acc[g], 0, 0, 0);
        }
        {   // h fragment: padded 144B rows (conflict-free b128)
            const char* hrow = bufb + BHOFF + lrow * 144;
            float4 a = *(const float4*)(hrow + q * 32);
            float4 b = *(const float4*)(hrow + q * 32 + 16);
            bf16x8 af;
            af[0]=(__bf16)a.x; af[1]=(__bf16)a.y; af[2]=(__bf16)a.z; af[3]=(__bf16)a.w;
            af[4]=(__bf16)b.x; af[5]=(__bf16)b.y; af[6]=(__bf16)b.z; af[7]=(__bf16)b.w;
#pragma unroll
            for (int g = 0; g < 4; ++g)
                acc[g] = __builtin_amdgcn_mfma_f32_16x16x32_bf16(af, bw[g][6], acc[g], 0, 0, 0);
        }

        // ---- epilogue: 8 global stores + py writes ----
        const long gbase = (long)t * TROWS;
#pragma unroll
        for (int jj = 0; jj < 4; ++jj) {
            const int r = drow + jj;
            float iv = fast_sigmoid(acc[0][jj] + bias[0]);
            float fv = fast_sigmoid(acc[1][jj] + bias[1]);
            float gv = fast_tanh   (acc[2][jj] + bias[2]);
            float ov = fast_sigmoid(acc[3][jj] + bias[3]);
            float cvv = *(const float*)(bufb + BCOFF + r * 128 + col * 4);
            float c0 = fv * cvv + iv * gv;
            float h0 = ov * fast_tanh(c0);
            long grow = gbase + r;
            p.c0o[grow * HID + col] = c0;
            p.h0o[grow * HID + col] = h0;
            float rl = fmaxf(h0, 0.f);
            float r0 = rl * wl0, r1 = rl * wl1;
            r0 += __shfl_xor(r0, 1); r0 += __shfl_xor(r0, 2);
            r0 += __shfl_xor(r0, 4); r0 += __shfl_xor(r0, 8);
            r1 += __shfl_xor(r1, 1); r1 += __shfl_xor(r1, 2);
            r1 += __shfl_xor(r1, 4); r1 += __shfl_xor(r1, 8);
            if (cl == 0) {
                py[((sub * 2 + hf) * 16 + 4 * q + jj) * 2 + 0] = r0;
                py[((sub * 2 + hf) * 16 + 4 * q + jj) * 2 + 1] = r1;
            }
        }
        asm volatile("s_waitcnt lgkmcnt(0)" ::: "memory");
        __builtin_amdgcn_s_barrier();
        asm volatile("" ::: "memory");

        // ---- y: wave w stores values v = w*16 + l (LAST vmem op of iter) ----
        if (l < 16) {
            int v = w * 16 + l;
            int r = v >> 1, k = v & 1;
            int s2 = r >> 4, r16 = r & 15;
            float yv = py[((s2 * 2 + 0) * 16 + r16) * 2 + k]
                     + py[((s2 * 2 + 1) * 16 + r16) * 2 + k]
                     + (k ? bl1 : bl0);
            p.y[gbase * 2 + v] = yv;
        }

        if (!more) break;
        par ^= 1; t = tn;
    }
}

extern "C" void kernel_launch(void* const* d_in, const int* in_sizes, int n_in,
                              void* d_out, int out_size, void* d_ws, size_t ws_size,
                              hipStream_t stream) {
    PrepParams pp;
    pp.W0  = (const float*)d_in[5];
    pp.W1  = (const float*)d_in[6];
    pp.W2  = (const float*)d_in[7];
    pp.W3  = (const float*)d_in[8];
    pp.b0  = (const float*)d_in[9];
    pp.b1  = (const float*)d_in[10];
    pp.b2  = (const float*)d_in[11];
    pp.b3  = (const float*)d_in[12];
    pp.Wc0 = (const float*)d_in[13];
    pp.Wc1 = (const float*)d_in[14];
    pp.Wc2 = (const float*)d_in[15];
    pp.Wc3 = (const float*)d_in[16];
    pp.bc0 = (const float*)d_in[17];
    pp.bc1 = (const float*)d_in[18];
    pp.bc2 = (const float*)d_in[19];
    pp.bc3 = (const float*)d_in[20];
    pp.ws  = (char*)d_ws;
    hipLaunchKernelGGL(gclstm_prep, dim3(15), dim3(256), 0, stream, pp);

    Params p;
    p.x  = (const float*)d_in[0];
    p.h  = (const float*)d_in[3];
    p.c  = (const float*)d_in[4];
    p.Wl = (const float*)d_in[21];
    p.bl = (const float*)d_in[22];
    p.ws = (const char*)d_ws;

    const int n = in_sizes[0] / F_IN;   // 500000 (divisible by TROWS)
    p.n  = n;
    p.nt = n / TROWS;                   // 15625

    float* out = (float*)d_out;
    p.y   = out;
    p.h0o = out + (long)n * 2;
    p.c0o = out + (long)n * 2 + (long)n * HID;

    // 2 blocks/CU x 256 CUs (LDS 63KB)
    hipLaunchKernelGGL(gclstm_main, dim3(512), dim3(256), 0, stream, p);
}